// Round 1
// baseline (2300.655 us; speedup 1.0000x reference)
//
#include <hip/hip_runtime.h>
#include <math.h>

// Problem constants (from reference setup_inputs): B=8, N=M=2048, D=3.
#define BB 8
#define NN 2048
#define MM 2048

constexpr int BLOCK = 256;
constexpr int PER = NN / BLOCK; // 8 m-values per thread

// ---------------------------------------------------------------------------
// log_weights: out = a > 0 ? log(max(a,1e-30)) : -1e5
// ---------------------------------------------------------------------------
__global__ void logw_kernel(const float* __restrict__ a, float* __restrict__ out, int n) {
    int i = blockIdx.x * blockDim.x + threadIdx.x;
    if (i < n) {
        float v = a[i];
        out[i] = (v > 0.f) ? logf(fmaxf(v, 1e-30f)) : -1e5f;
    }
}

// ---------------------------------------------------------------------------
// softmin: out[b,n] = -eps * logsumexp_m( wlog[b,m] + pot[b,m]/eps - C(p_bn,q_bm)/eps )
//   C = acos(clip(<p,q>, -1+1e-6, 1-1e-6)) * 0.5
// If avg != null: out = 0.5*(avg[b,n] + result)   (the symmetrized update)
// One block per (n, b) = (blockIdx.x, blockIdx.y). NQ fixed at 2048.
// ---------------------------------------------------------------------------
__global__ __launch_bounds__(BLOCK)
void softmin_kernel(const float* __restrict__ P,    // (B, NP, 3)
                    const float* __restrict__ Q,    // (B, 2048, 3)
                    const float* __restrict__ wlog, // (B, 2048)
                    const float* __restrict__ pot,  // (B, 2048) or null
                    const float* __restrict__ avg,  // (B, NP) or null
                    float* __restrict__ out,        // (B, NP)
                    float eps, float inv_eps)
{
    const int n   = blockIdx.x;
    const int b   = blockIdx.y;
    const int tid = threadIdx.x;
    const int NP  = gridDim.x;

    const size_t poff = ((size_t)b * NP + n) * 3;
    const float px = P[poff], py = P[poff + 1], pz = P[poff + 2];

    const float* qb   = Q    + (size_t)b * NN * 3;
    const float* gb   = wlog + (size_t)b * NN;
    const float* potb = pot ? (pot + (size_t)b * NN) : nullptr;

    float v[PER];
    float mx = -INFINITY;
#pragma unroll
    for (int i = 0; i < PER; i++) {
        const int m = tid + i * BLOCK;
        const float qx = qb[3 * m + 0];
        const float qy = qb[3 * m + 1];
        const float qz = qb[3 * m + 2];
        float t = fmaf(px, qx, fmaf(py, qy, pz * qz));
        t = fminf(fmaxf(t, -1.f + 1e-6f), 1.f - 1e-6f);
        const float c = acosf(t) * 0.5f;
        float g = gb[m];
        if (potb) g = fmaf(potb[m], inv_eps, g);
        v[i] = fmaf(-c, inv_eps, g);
        mx = fmaxf(mx, v[i]);
    }
    float s = 0.f;
#pragma unroll
    for (int i = 0; i < PER; i++) s += expf(v[i] - mx);

    // 64-lane wave reduction of (max, sum) pairs
    for (int off = 32; off > 0; off >>= 1) {
        const float mo = __shfl_xor(mx, off);
        const float so = __shfl_xor(s, off);
        const float mn = fmaxf(mx, mo);
        s  = s * expf(mx - mn) + so * expf(mo - mn);
        mx = mn;
    }
    __shared__ float sm[4], ss[4];
    const int wave = tid >> 6, lane = tid & 63;
    if (lane == 0) { sm[wave] = mx; ss[wave] = s; }
    __syncthreads();
    if (tid == 0) {
        float M0 = sm[0], S0 = ss[0];
#pragma unroll
        for (int w = 1; w < 4; w++) {
            const float mn = fmaxf(M0, sm[w]);
            S0 = S0 * expf(M0 - mn) + ss[w] * expf(sm[w] - mn);
            M0 = mn;
        }
        float res = -eps * (M0 + logf(S0));
        if (avg) res = 0.5f * (avg[(size_t)b * NP + n] + res);
        out[(size_t)b * NP + n] = res;
    }
}

// ---------------------------------------------------------------------------
// out[b] = sum_n alpha[b,n]*(b_x-a_x)[b,n] + sum_m beta[b,m]*(a_y-b_y)[b,m]
// ---------------------------------------------------------------------------
__global__ __launch_bounds__(BLOCK)
void reduce_kernel(const float* __restrict__ alpha, const float* __restrict__ beta,
                   const float* __restrict__ a_x, const float* __restrict__ b_x,
                   const float* __restrict__ a_y, const float* __restrict__ b_y,
                   float* __restrict__ out)
{
    const int b = blockIdx.x;
    const int tid = threadIdx.x;
    float acc = 0.f;
    for (int n = tid; n < NN; n += BLOCK) {
        const size_t i = (size_t)b * NN + n;
        acc += alpha[i] * (b_x[i] - a_x[i]);
    }
    for (int m = tid; m < MM; m += BLOCK) {
        const size_t i = (size_t)b * MM + m;
        acc += beta[i] * (a_y[i] - b_y[i]);
    }
    __shared__ float red[BLOCK];
    red[tid] = acc;
    __syncthreads();
    for (int st = BLOCK / 2; st > 0; st >>= 1) {
        if (tid < st) red[tid] += red[tid + st];
        __syncthreads();
    }
    if (tid == 0) out[b] = red[0];
}

// ---------------------------------------------------------------------------
extern "C" void kernel_launch(void* const* d_in, const int* in_sizes, int n_in,
                              void* d_out, int out_size, void* d_ws, size_t ws_size,
                              hipStream_t stream)
{
    const float* alpha = (const float*)d_in[0]; // (B,N)
    const float* x     = (const float*)d_in[1]; // (B,N,3)
    const float* beta  = (const float*)d_in[2]; // (B,M)
    const float* y     = (const float*)d_in[3]; // (B,M,3)
    float* out = (float*)d_out;                 // (B,)
    float* ws  = (float*)d_ws;

    const size_t S = (size_t)BB * NN; // 16384 floats per potential array

    float* al = ws;
    float* bl = ws + S;
    // double-buffered potentials: [cur 4][nxt 4]
    float* buf[8];
    for (int i = 0; i < 8; i++) buf[i] = ws + (2 + i) * S;
    float *a_x = buf[0], *b_y = buf[1], *a_y = buf[2], *b_x = buf[3];
    float *a_xn = buf[4], *b_yn = buf[5], *a_yn = buf[6], *b_xn = buf[7];

    // eps schedule: [d^2] + exp(arange(2ln d, 2ln blur, 2ln 0.5)) + [blur^2]
    const float EPS[8] = {4.0f, 4.0f, 1.0f, 0.25f, 0.0625f, 0.015625f, 0.00390625f, 0.0025f};

    // log weights
    logw_kernel<<<(int)((S + BLOCK - 1) / BLOCK), BLOCK, 0, stream>>>(alpha, al, (int)S);
    logw_kernel<<<(int)((S + BLOCK - 1) / BLOCK), BLOCK, 0, stream>>>(beta,  bl, (int)S);

    const dim3 gN(NN, BB), gM(MM, BB);

    // ---- init at eps = EPS[0] ----
    {
        const float e = EPS[0], ie = 1.0f / e;
        softmin_kernel<<<gN, BLOCK, 0, stream>>>(x, x, al, nullptr, nullptr, a_x, e, ie);
        softmin_kernel<<<gM, BLOCK, 0, stream>>>(y, y, bl, nullptr, nullptr, b_y, e, ie);
        softmin_kernel<<<gM, BLOCK, 0, stream>>>(y, x, al, nullptr, nullptr, a_y, e, ie);
        softmin_kernel<<<gN, BLOCK, 0, stream>>>(x, y, bl, nullptr, nullptr, b_x, e, ie);
    }

    // ---- annealed symmetrized loop ----
    for (int k = 0; k < 8; k++) {
        const float e = EPS[k], ie = 1.0f / e;
        softmin_kernel<<<gN, BLOCK, 0, stream>>>(x, x, al, a_x, a_x, a_xn, e, ie);
        softmin_kernel<<<gM, BLOCK, 0, stream>>>(y, y, bl, b_y, b_y, b_yn, e, ie);
        softmin_kernel<<<gM, BLOCK, 0, stream>>>(y, x, al, b_x, a_y, a_yn, e, ie);
        softmin_kernel<<<gN, BLOCK, 0, stream>>>(x, y, bl, a_y, b_x, b_xn, e, ie);
        // swap cur <-> nxt
        float* t;
        t = a_x; a_x = a_xn; a_xn = t;
        t = b_y; b_y = b_yn; b_yn = t;
        t = a_y; a_y = a_yn; a_yn = t;
        t = b_x; b_x = b_xn; b_xn = t;
    }

    // ---- final extrapolation at eps = blur^2 ----
    {
        const float e = EPS[7], ie = 1.0f / e;
        softmin_kernel<<<gN, BLOCK, 0, stream>>>(x, x, al, a_x, nullptr, a_xn, e, ie);
        softmin_kernel<<<gM, BLOCK, 0, stream>>>(y, y, bl, b_y, nullptr, b_yn, e, ie);
        softmin_kernel<<<gM, BLOCK, 0, stream>>>(y, x, al, b_x, nullptr, a_yn, e, ie);
        softmin_kernel<<<gN, BLOCK, 0, stream>>>(x, y, bl, a_y, nullptr, b_xn, e, ie);
    }

    // ---- final loss reduction ----
    reduce_kernel<<<BB, BLOCK, 0, stream>>>(alpha, beta, a_xn, b_xn, a_yn, b_yn, out);
}

// Round 2
// 1724.657 us; speedup vs baseline: 1.3340x; 1.3340x over previous
//
#include <hip/hip_runtime.h>
#include <math.h>

// Problem constants (from reference setup_inputs): B=8, N=M=2048, D=3.
#define BB 8
#define NN 2048

constexpr int BLOCK = 256;           // 4 waves
constexpr int ROWS_PER_BLOCK = 8;    // 4 waves x 2 rows each
constexpr int PER = NN / 64;         // 32 m-values per lane

#define L2E 1.4426950408889634f
#define LN2 0.6931471805599453f

// ---------------------------------------------------------------------------
// pack: pk[i] = {px, py, pz, log_weights(w)*log2(e)}
// ---------------------------------------------------------------------------
__global__ void pack_kernel(const float* __restrict__ pts, const float* __restrict__ w,
                            float4* __restrict__ pk, int n) {
    int i = blockIdx.x * blockDim.x + threadIdx.x;
    if (i < n) {
        float wv = w[i];
        float lw = (wv > 0.f) ? logf(fmaxf(wv, 1e-30f)) : -1e5f;
        pk[i] = make_float4(pts[3 * i], pts[3 * i + 1], pts[3 * i + 2], lw * L2E);
    }
}

// A&S 4.4.46 8-coeff: acos(x) = sqrt(1-x) * p(x) on [0,1], |err| <= 2e-8
__device__ __forceinline__ float acos_fast(float x) {
    float u = fabsf(x);
    float p = fmaf(u, -0.0012624911f, 0.0066700901f);
    p = fmaf(u, p, -0.0170881256f);
    p = fmaf(u, p, 0.0308918810f);
    p = fmaf(u, p, -0.0501743046f);
    p = fmaf(u, p, 0.0889789874f);
    p = fmaf(u, p, -0.2145988016f);
    p = fmaf(u, p, 1.5707963050f);
    float r = __builtin_amdgcn_sqrtf(1.0f - u) * p;
    return (x >= 0.f) ? r : (3.14159265358979f - r);
}

// ---------------------------------------------------------------------------
// softmin: out[b,n] = -eps * logsumexp_m( wlog[b,m] + pot[b,m]/eps - C/eps )
//   C = acos(clip(<p,q>, -1+1e-6, 1-1e-6)) * 0.5
// All internal math in log2 domain (hardware v_exp_f32 / v_log_f32).
// One wave per 2 rows; block = 4 waves = 8 rows. NQ fixed at 2048.
// If avg != null: out = 0.5*(avg + result).
// ---------------------------------------------------------------------------
__global__ __launch_bounds__(BLOCK, 2)
void softmin_kernel(const float* __restrict__ P,    // (B, NP, 3) row points
                    const float4* __restrict__ QK,  // (B, 2048) packed {q, wlog*L2E}
                    const float* __restrict__ pot,  // (B, 2048) or null
                    const float* __restrict__ avg,  // (B, NP) or null
                    float* __restrict__ out,        // (B, NP)
                    float eps, float inv_eps, int NP)
{
    const int b    = blockIdx.y;
    const int wave = threadIdx.x >> 6;
    const int lane = threadIdx.x & 63;
    const int n0   = blockIdx.x * ROWS_PER_BLOCK + wave * 2;

    const float ieL = inv_eps * L2E;          // pot scale (log2 domain)
    const float ieh = 0.5f * inv_eps * L2E;   // acos scale (0.5 folded in)

    const size_t po = ((size_t)b * NP + n0) * 3;
    const float p0x = P[po + 0], p0y = P[po + 1], p0z = P[po + 2];
    const float p1x = P[po + 3], p1y = P[po + 4], p1z = P[po + 5];

    const float4* qb   = QK + (size_t)b * NN;
    const float*  potb = pot ? (pot + (size_t)b * NN) : nullptr;

    float v0[PER], v1[PER];
    float mx0 = -INFINITY, mx1 = -INFINITY;

#pragma unroll
    for (int i = 0; i < PER; i++) {
        const int m = i * 64 + lane;
        const float4 q = qb[m];
        float g = q.w;                               // wlog * L2E
        if (potb) g = fmaf(potb[m], ieL, g);
        // row 0
        float t0 = fmaf(p0x, q.x, fmaf(p0y, q.y, p0z * q.z));
        t0 = fminf(fmaxf(t0, -1.f + 1e-6f), 1.f - 1e-6f);
        v0[i] = fmaf(acos_fast(t0), -ieh, g);
        mx0 = fmaxf(mx0, v0[i]);
        // row 1
        float t1 = fmaf(p1x, q.x, fmaf(p1y, q.y, p1z * q.z));
        t1 = fminf(fmaxf(t1, -1.f + 1e-6f), 1.f - 1e-6f);
        v1[i] = fmaf(acos_fast(t1), -ieh, g);
        mx1 = fmaxf(mx1, v1[i]);
    }

    // wave-wide max (fmax-only butterfly — no exp in reduction)
#pragma unroll
    for (int off = 32; off; off >>= 1) {
        mx0 = fmaxf(mx0, __shfl_xor(mx0, off));
        mx1 = fmaxf(mx1, __shfl_xor(mx1, off));
    }

    float s0 = 0.f, s1 = 0.f;
#pragma unroll
    for (int i = 0; i < PER; i++) {
        s0 += __builtin_amdgcn_exp2f(v0[i] - mx0);
        s1 += __builtin_amdgcn_exp2f(v1[i] - mx1);
    }
#pragma unroll
    for (int off = 32; off; off >>= 1) {
        s0 += __shfl_xor(s0, off);
        s1 += __shfl_xor(s1, off);
    }

    if (lane == 0) {
        const float epsln2 = eps * LN2;
        float r0 = -epsln2 * (mx0 + __builtin_amdgcn_logf(s0));
        float r1 = -epsln2 * (mx1 + __builtin_amdgcn_logf(s1));
        const size_t o = (size_t)b * NP + n0;
        if (avg) {
            r0 = 0.5f * (avg[o] + r0);
            r1 = 0.5f * (avg[o + 1] + r1);
        }
        out[o] = r0;
        out[o + 1] = r1;
    }
}

// ---------------------------------------------------------------------------
// out[b] = sum_n alpha*(b_x-a_x) + sum_m beta*(a_y-b_y)
// ---------------------------------------------------------------------------
__global__ __launch_bounds__(BLOCK)
void reduce_kernel(const float* __restrict__ alpha, const float* __restrict__ beta,
                   const float* __restrict__ a_x, const float* __restrict__ b_x,
                   const float* __restrict__ a_y, const float* __restrict__ b_y,
                   float* __restrict__ out)
{
    const int b = blockIdx.x;
    const int tid = threadIdx.x;
    float acc = 0.f;
    for (int n = tid; n < NN; n += BLOCK) {
        const size_t i = (size_t)b * NN + n;
        acc += alpha[i] * (b_x[i] - a_x[i]);
        acc += beta[i] * (a_y[i] - b_y[i]);
    }
    __shared__ float red[BLOCK];
    red[tid] = acc;
    __syncthreads();
    for (int st = BLOCK / 2; st > 0; st >>= 1) {
        if (tid < st) red[tid] += red[tid + st];
        __syncthreads();
    }
    if (tid == 0) out[b] = red[0];
}

// ---------------------------------------------------------------------------
extern "C" void kernel_launch(void* const* d_in, const int* in_sizes, int n_in,
                              void* d_out, int out_size, void* d_ws, size_t ws_size,
                              hipStream_t stream)
{
    const float* alpha = (const float*)d_in[0]; // (B,N)
    const float* x     = (const float*)d_in[1]; // (B,N,3)
    const float* beta  = (const float*)d_in[2]; // (B,M)
    const float* y     = (const float*)d_in[3]; // (B,M,3)
    float* out = (float*)d_out;                 // (B,)
    float* ws  = (float*)d_ws;

    const size_t S = (size_t)BB * NN; // 16384 floats per potential array

    // packed arrays: PX = {x, log(alpha)*L2E}, PY = {y, log(beta)*L2E}
    float4* PX = (float4*)ws;                    // S float4 = 4S floats
    float4* PY = (float4*)(ws + 4 * S);
    float* base = ws + 8 * S;
    float* buf[8];
    for (int i = 0; i < 8; i++) buf[i] = base + i * S;
    float *a_x = buf[0], *b_y = buf[1], *a_y = buf[2], *b_x = buf[3];
    float *a_xn = buf[4], *b_yn = buf[5], *a_yn = buf[6], *b_xn = buf[7];

    // eps schedule: [d^2] + exp(arange(2ln d, 2ln blur, 2ln 0.5)) + [blur^2]
    const float EPS[8] = {4.0f, 4.0f, 1.0f, 0.25f, 0.0625f, 0.015625f, 0.00390625f, 0.0025f};

    pack_kernel<<<(int)(S / BLOCK), BLOCK, 0, stream>>>(x, alpha, PX, (int)S);
    pack_kernel<<<(int)(S / BLOCK), BLOCK, 0, stream>>>(y, beta,  PY, (int)S);

    const dim3 g(NN / ROWS_PER_BLOCK, BB);

    // ---- init at eps = EPS[0] ----
    {
        const float e = EPS[0], ie = 1.0f / e;
        softmin_kernel<<<g, BLOCK, 0, stream>>>(x, PX, nullptr, nullptr, a_x, e, ie, NN);
        softmin_kernel<<<g, BLOCK, 0, stream>>>(y, PY, nullptr, nullptr, b_y, e, ie, NN);
        softmin_kernel<<<g, BLOCK, 0, stream>>>(y, PX, nullptr, nullptr, a_y, e, ie, NN);
        softmin_kernel<<<g, BLOCK, 0, stream>>>(x, PY, nullptr, nullptr, b_x, e, ie, NN);
    }

    // ---- annealed symmetrized loop ----
    for (int k = 0; k < 8; k++) {
        const float e = EPS[k], ie = 1.0f / e;
        softmin_kernel<<<g, BLOCK, 0, stream>>>(x, PX, a_x, a_x, a_xn, e, ie, NN);
        softmin_kernel<<<g, BLOCK, 0, stream>>>(y, PY, b_y, b_y, b_yn, e, ie, NN);
        softmin_kernel<<<g, BLOCK, 0, stream>>>(y, PX, b_x, a_y, a_yn, e, ie, NN);
        softmin_kernel<<<g, BLOCK, 0, stream>>>(x, PY, a_y, b_x, b_xn, e, ie, NN);
        float* t;
        t = a_x; a_x = a_xn; a_xn = t;
        t = b_y; b_y = b_yn; b_yn = t;
        t = a_y; a_y = a_yn; a_yn = t;
        t = b_x; b_x = b_xn; b_xn = t;
    }

    // ---- final extrapolation at eps = blur^2 ----
    {
        const float e = EPS[7], ie = 1.0f / e;
        softmin_kernel<<<g, BLOCK, 0, stream>>>(x, PX, a_x, nullptr, a_xn, e, ie, NN);
        softmin_kernel<<<g, BLOCK, 0, stream>>>(y, PY, b_y, nullptr, b_yn, e, ie, NN);
        softmin_kernel<<<g, BLOCK, 0, stream>>>(y, PX, b_x, nullptr, a_yn, e, ie, NN);
        softmin_kernel<<<g, BLOCK, 0, stream>>>(x, PY, a_y, nullptr, b_xn, e, ie, NN);
    }

    // ---- final loss reduction ----
    reduce_kernel<<<BB, BLOCK, 0, stream>>>(alpha, beta, a_xn, b_xn, a_yn, b_yn, out);
}

// Round 3
// 815.395 us; speedup vs baseline: 2.8215x; 2.1151x over previous
//
#include <hip/hip_runtime.h>
#include <math.h>

// Problem constants (from reference setup_inputs): B=8, N=M=2048, D=3.
#define BB 8
#define NN 2048

constexpr int BLOCK = 256;      // 4 waves
constexpr int RPW   = 4;        // rows per wave
constexpr int RPB   = 16;       // rows per block (4 waves x 4 rows)
constexpr int ITERS = NN / 64;  // 32 column-iterations per wave
constexpr int CHUNK = 8;        // online-softmax chunk (register v[RPW][CHUNK])

#define L2E 1.4426950408889634f
#define LN2 0.6931471805599453f

// ---------------------------------------------------------------------------
// pack: pk[i] = {px, py, pz, log_weights(w)*log2(e)}
// ---------------------------------------------------------------------------
__global__ void pack_kernel(const float* __restrict__ pts, const float* __restrict__ w,
                            float4* __restrict__ pk, int n) {
    int i = blockIdx.x * blockDim.x + threadIdx.x;
    if (i < n) {
        float wv = w[i];
        float lw = (wv > 0.f) ? logf(fmaxf(wv, 1e-30f)) : -1e5f;
        pk[i] = make_float4(pts[3 * i], pts[3 * i + 1], pts[3 * i + 2], lw * L2E);
    }
}

// A&S 4.4.46 8-coeff: acos(x) = sqrt(1-x) * p(x) on [0,1], |err| <= 2e-8
__device__ __forceinline__ float acos_fast(float x) {
    float u = fabsf(x);
    float p = fmaf(u, -0.0012624911f, 0.0066700901f);
    p = fmaf(u, p, -0.0170881256f);
    p = fmaf(u, p, 0.0308918810f);
    p = fmaf(u, p, -0.0501743046f);
    p = fmaf(u, p, 0.0889789874f);
    p = fmaf(u, p, -0.2145988016f);
    p = fmaf(u, p, 1.5707963050f);
    float r = __builtin_amdgcn_sqrtf(1.0f - u) * p;
    return (x >= 0.f) ? r : (3.14159265358979f - r);
}

// ---------------------------------------------------------------------------
// Fused softmin: 4 independent (P,QK,pot,avg,out) problems per launch,
// selected by blockIdx.z. Q (+pot folded into .w) staged in LDS (32 KB).
// out[b,n] = -eps * lse_m( wlog + pot/eps - acos(<p,q>)/2/eps )
// If avg != null: out = 0.5*(avg + result).
// ---------------------------------------------------------------------------
struct SoftminArgs {
    const float*  P[4];    // (B, NP, 3) row points
    const float4* QK[4];   // (B, 2048)  packed {q, wlog*L2E}
    const float*  pot[4];  // (B, 2048)  or null
    const float*  avg[4];  // (B, NP)    or null
    float*        out[4];  // (B, NP)
};

__global__ __launch_bounds__(BLOCK)
void softmin4_kernel(SoftminArgs args, float eps, float inv_eps, int NP)
{
    __shared__ float4 lds[NN];  // 32 KB: {qx,qy,qz, g = wlog*L2E + pot/eps*L2E}

    const int var = blockIdx.z;
    const int b   = blockIdx.y;
    const int tid = threadIdx.x;

    const float*  P   = args.P[var];
    const float4* QK  = args.QK[var];
    const float*  pot = args.pot[var];
    const float*  avg = args.avg[var];
    float*        out = args.out[var];

    const float ieL = inv_eps * L2E;          // pot scale (log2 domain)
    const float ieh = 0.5f * inv_eps * L2E;   // acos scale (0.5 folded in)

    // ---- stage Q (+pot) into LDS ----
    const float4* qb = QK + (size_t)b * NN;
    if (pot) {
        const float* potb = pot + (size_t)b * NN;
        for (int i = tid; i < NN; i += BLOCK) {
            float4 q = qb[i];
            q.w = fmaf(potb[i], ieL, q.w);
            lds[i] = q;
        }
    } else {
        for (int i = tid; i < NN; i += BLOCK) lds[i] = qb[i];
    }
    __syncthreads();

    const int wave = tid >> 6, lane = tid & 63;
    const int n0 = blockIdx.x * RPB + wave * RPW;

    const size_t po = ((size_t)b * NP + n0) * 3;
    float px[RPW], py[RPW], pz[RPW];
#pragma unroll
    for (int r = 0; r < RPW; r++) {
        px[r] = P[po + 3 * r + 0];
        py[r] = P[po + 3 * r + 1];
        pz[r] = P[po + 3 * r + 2];
    }

    float mx[RPW], sm[RPW];
#pragma unroll
    for (int r = 0; r < RPW; r++) { mx[r] = -INFINITY; sm[r] = 0.f; }

    for (int c0 = 0; c0 < ITERS; c0 += CHUNK) {
        float v[RPW][CHUNK];
        float cm[RPW];
#pragma unroll
        for (int r = 0; r < RPW; r++) cm[r] = -INFINITY;
#pragma unroll
        for (int j = 0; j < CHUNK; j++) {
            const float4 q = lds[(c0 + j) * 64 + lane];
#pragma unroll
            for (int r = 0; r < RPW; r++) {
                float t = fmaf(px[r], q.x, fmaf(py[r], q.y, pz[r] * q.z));
                t = fminf(fmaxf(t, -1.f + 1e-6f), 1.f - 1e-6f);
                v[r][j] = fmaf(acos_fast(t), -ieh, q.w);
                cm[r] = fmaxf(cm[r], v[r][j]);
            }
        }
        // chunk merge: one rescale of running sum, then 8 exp2 per row
#pragma unroll
        for (int r = 0; r < RPW; r++) {
            const float nm = fmaxf(mx[r], cm[r]);
            float acc = sm[r] * __builtin_amdgcn_exp2f(mx[r] - nm);
#pragma unroll
            for (int j = 0; j < CHUNK; j++)
                acc += __builtin_amdgcn_exp2f(v[r][j] - nm);
            sm[r] = acc;
            mx[r] = nm;
        }
    }

    // ---- wave reduction: fmax butterfly, one rescale, sum butterfly ----
    float res[RPW];
#pragma unroll
    for (int r = 0; r < RPW; r++) {
        float gm = mx[r];
#pragma unroll
        for (int off = 32; off; off >>= 1) gm = fmaxf(gm, __shfl_xor(gm, off));
        float sr = sm[r] * __builtin_amdgcn_exp2f(mx[r] - gm);
#pragma unroll
        for (int off = 32; off; off >>= 1) sr += __shfl_xor(sr, off);
        res[r] = -eps * LN2 * (gm + __builtin_amdgcn_logf(sr));
    }

    if (lane == 0) {
        const size_t o = (size_t)b * NP + n0;
        float4 w = make_float4(res[0], res[1], res[2], res[3]);
        if (avg) {
            const float4 a = *(const float4*)(avg + o);
            w.x = 0.5f * (w.x + a.x);
            w.y = 0.5f * (w.y + a.y);
            w.z = 0.5f * (w.z + a.z);
            w.w = 0.5f * (w.w + a.w);
        }
        *(float4*)(out + o) = w;
    }
}

// ---------------------------------------------------------------------------
// out[b] = sum_n alpha*(b_x-a_x) + sum_m beta*(a_y-b_y)
// ---------------------------------------------------------------------------
__global__ __launch_bounds__(BLOCK)
void reduce_kernel(const float* __restrict__ alpha, const float* __restrict__ beta,
                   const float* __restrict__ a_x, const float* __restrict__ b_x,
                   const float* __restrict__ a_y, const float* __restrict__ b_y,
                   float* __restrict__ out)
{
    const int b = blockIdx.x;
    const int tid = threadIdx.x;
    float acc = 0.f;
    for (int n = tid; n < NN; n += BLOCK) {
        const size_t i = (size_t)b * NN + n;
        acc += alpha[i] * (b_x[i] - a_x[i]);
        acc += beta[i] * (a_y[i] - b_y[i]);
    }
    __shared__ float red[BLOCK];
    red[tid] = acc;
    __syncthreads();
    for (int st = BLOCK / 2; st > 0; st >>= 1) {
        if (tid < st) red[tid] += red[tid + st];
        __syncthreads();
    }
    if (tid == 0) out[b] = red[0];
}

// ---------------------------------------------------------------------------
extern "C" void kernel_launch(void* const* d_in, const int* in_sizes, int n_in,
                              void* d_out, int out_size, void* d_ws, size_t ws_size,
                              hipStream_t stream)
{
    const float* alpha = (const float*)d_in[0]; // (B,N)
    const float* x     = (const float*)d_in[1]; // (B,N,3)
    const float* beta  = (const float*)d_in[2]; // (B,M)
    const float* y     = (const float*)d_in[3]; // (B,M,3)
    float* out = (float*)d_out;                 // (B,)
    float* ws  = (float*)d_ws;

    const size_t S = (size_t)BB * NN; // 16384 floats per potential array

    // packed arrays: PX = {x, log(alpha)*L2E}, PY = {y, log(beta)*L2E}
    float4* PX = (float4*)ws;                    // S float4 = 4S floats
    float4* PY = (float4*)(ws + 4 * S);
    float* base = ws + 8 * S;
    float* buf[8];
    for (int i = 0; i < 8; i++) buf[i] = base + i * S;
    float *a_x = buf[0], *b_y = buf[1], *a_y = buf[2], *b_x = buf[3];
    float *a_xn = buf[4], *b_yn = buf[5], *a_yn = buf[6], *b_xn = buf[7];

    // eps schedule: [d^2] + exp(arange(2ln d, 2ln blur, 2ln 0.5)) + [blur^2]
    const float EPS[8] = {4.0f, 4.0f, 1.0f, 0.25f, 0.0625f, 0.015625f, 0.00390625f, 0.0025f};

    pack_kernel<<<(int)(S / BLOCK), BLOCK, 0, stream>>>(x, alpha, PX, (int)S);
    pack_kernel<<<(int)(S / BLOCK), BLOCK, 0, stream>>>(y, beta,  PY, (int)S);

    const dim3 g(NN / RPB, BB, 4);

    // variant order: 0: a_x (P=x,QK=PX), 1: b_y (P=y,QK=PY),
    //                2: a_y (P=y,QK=PX), 3: b_x (P=x,QK=PY)
    SoftminArgs A;
    A.P[0] = x; A.P[1] = y; A.P[2] = y; A.P[3] = x;
    A.QK[0] = PX; A.QK[1] = PY; A.QK[2] = PX; A.QK[3] = PY;

    // ---- init at eps = EPS[0] ----
    {
        const float e = EPS[0], ie = 1.0f / e;
        for (int v = 0; v < 4; v++) { A.pot[v] = nullptr; A.avg[v] = nullptr; }
        A.out[0] = a_x; A.out[1] = b_y; A.out[2] = a_y; A.out[3] = b_x;
        softmin4_kernel<<<g, BLOCK, 0, stream>>>(A, e, ie, NN);
    }

    // ---- annealed symmetrized loop ----
    for (int k = 0; k < 8; k++) {
        const float e = EPS[k], ie = 1.0f / e;
        A.pot[0] = a_x; A.pot[1] = b_y; A.pot[2] = b_x; A.pot[3] = a_y;
        A.avg[0] = a_x; A.avg[1] = b_y; A.avg[2] = a_y; A.avg[3] = b_x;
        A.out[0] = a_xn; A.out[1] = b_yn; A.out[2] = a_yn; A.out[3] = b_xn;
        softmin4_kernel<<<g, BLOCK, 0, stream>>>(A, e, ie, NN);
        float* t;
        t = a_x; a_x = a_xn; a_xn = t;
        t = b_y; b_y = b_yn; b_yn = t;
        t = a_y; a_y = a_yn; a_yn = t;
        t = b_x; b_x = b_xn; b_xn = t;
    }

    // ---- final extrapolation at eps = blur^2 ----
    {
        const float e = EPS[7], ie = 1.0f / e;
        A.pot[0] = a_x; A.pot[1] = b_y; A.pot[2] = b_x; A.pot[3] = a_y;
        for (int v = 0; v < 4; v++) A.avg[v] = nullptr;
        A.out[0] = a_xn; A.out[1] = b_yn; A.out[2] = a_yn; A.out[3] = b_xn;
        softmin4_kernel<<<g, BLOCK, 0, stream>>>(A, e, ie, NN);
    }

    // ---- final loss reduction ----
    reduce_kernel<<<BB, BLOCK, 0, stream>>>(alpha, beta, a_xn, b_xn, a_yn, b_yn, out);
}

// Round 4
// 708.303 us; speedup vs baseline: 3.2481x; 1.1512x over previous
//
#include <hip/hip_runtime.h>
#include <math.h>

// Problem constants: B=8, N=M=2048, D=3.
#define BB 8
#define NN 2048
#define L2E 1.4426950408889634f
#define LN2 0.6931471805599453f
#define PI_F 3.14159265358979f

constexpr int TB    = 128;               // tile edge
constexpr int T16   = NN / TB;           // 16 tile-blocks per dim
constexpr int SLOTS = T16;               // partial slots per row
constexpr int NXX   = T16 * (T16 + 1) / 2;   // 136 triangular tiles
constexpr int NT    = 2 * NXX + T16 * T16;   // 528 tiles per batch
constexpr int SARR  = BB * NN;           // 16384 elems per potential array

// ---------------------------------------------------------------------------
// pack: log-weights in log2 domain, replicated into the initial g arrays
// ---------------------------------------------------------------------------
__global__ void pack_kernel(const float* __restrict__ a, const float* __restrict__ bw,
                            float* gxw, float* gyw, float* gA, float* gB,
                            float* gXs, float* gYs, int n) {
    int i = blockIdx.x * blockDim.x + threadIdx.x;
    if (i < n) {
        float va = a[i];
        float g = ((va > 0.f) ? logf(fmaxf(va, 1e-30f)) : -1e5f) * L2E;
        gxw[i] = g; gA[i] = g; gXs[i] = g;
        float vb = bw[i];
        float h = ((vb > 0.f) ? logf(fmaxf(vb, 1e-30f)) : -1e5f) * L2E;
        gyw[i] = h; gB[i] = h; gYs[i] = h;
    }
}

// ---------------------------------------------------------------------------
// Tile kernel: computes ach = acos(<p,q>)*0.5/eps*log2(e) ONCE per (n,m) pair
// and serves BOTH reduction directions. Emits per-tile (max,sum) partials.
//   kind 0: xx (I<=J)  -> row-dir & col-dir both feed pAX
//   kind 1: yy (I<=J)  -> pBY
//   kind 2: xy (all)   -> row-dir feeds pBX (x-indexed), col-dir pAY (y-indexed)
// Diagonal xx/yy tiles: full tile via row-dir only (col-dir skipped).
// ---------------------------------------------------------------------------
struct TileArgs {
    const float* x; const float* y;
    const float* gA; const float* gB; const float* gXs; const float* gYs;
    float2* pAX; float2* pBY; float2* pAY; float2* pBX;
};

__global__ __launch_bounds__(256)
void tile_kernel(TileArgs A, float ieh, float pi_ieh)
{
    __shared__ __align__(16) float achT[64][132];   // 33.8 KB, pad 132 (mult of 4)
    __shared__ float4 p1s[TB], p2s[TB];
    __shared__ float  g1s[TB], g2s[TB];
    __shared__ float2 colAcc[TB];
    __shared__ float2 mredC[TB][8];
    __shared__ float2 mredR[64][4];

    const int b = blockIdx.y;
    const int t = threadIdx.x;
    int bx = blockIdx.x;

    int kind, I, J;
    if (bx < NXX) { kind = 0; }
    else if (bx < 2 * NXX) { kind = 1; bx -= NXX; }
    else { kind = 2; bx -= 2 * NXX; }
    if (kind < 2) {
        int idx = bx; I = 0;
        for (;;) { int len = T16 - I; if (idx < len) { J = I + idx; break; } idx -= len; I++; }
    } else { I = bx >> 4; J = bx & 15; }

    const float* P1 = (kind == 1) ? A.y : A.x;
    const float* P2 = (kind == 0) ? A.x : A.y;
    const float* g1 = (kind == 0) ? A.gA : (kind == 1) ? A.gB : A.gXs;  // row-side (col-dir)
    const float* g2 = (kind == 0) ? A.gA : (kind == 1) ? A.gB : A.gYs;  // col-side (row-dir)
    float2* rowArr = (kind == 0) ? A.pAX : (kind == 1) ? A.pBY : A.pBX;
    float2* colArr = (kind == 0) ? A.pAX : (kind == 1) ? A.pBY : A.pAY;
    const bool diag = (kind < 2) && (I == J);

    // ---- stage points + weights ----
    if (t < TB) {
        size_t gi = (size_t)b * NN + (size_t)I * TB + t;
        p1s[t] = make_float4(P1[gi * 3], P1[gi * 3 + 1], P1[gi * 3 + 2], 0.f);
        g1s[t] = g1[gi];
        colAcc[t] = make_float2(-INFINITY, 0.f);
    } else {
        int u = t - TB;
        size_t gi = (size_t)b * NN + (size_t)J * TB + u;
        p2s[u] = make_float4(P2[gi * 3], P2[gi * 3 + 1], P2[gi * 3 + 2], 0.f);
        g2s[u] = g2[gi];
    }
    __syncthreads();

    // acos poly (A&S 4.4.45), coefficients pre-scaled by ieh
    const float K0 = 1.5707288f * ieh, K1 = -0.2121144f * ieh;
    const float K2 = 0.0742610f * ieh, K3 = -0.0187293f * ieh;

    const int cg = t & 31, c0 = cg * 4;   // 4 cols per thread
    const int rg = t >> 5;                // 8 row-groups x 8 rows

    float qx[4], qy[4], qz[4];
#pragma unroll
    for (int m = 0; m < 4; m++) { float4 q = p2s[c0 + m]; qx[m] = q.x; qy[m] = q.y; qz[m] = q.z; }

    for (int si = 0; si < 2; si++) {
        const int R0 = si * 64;
        // ---- compute ach (+ inline col-dir partials) ----
        float v[4][8];
#pragma unroll
        for (int i = 0; i < 8; i++) {
            const int nl = rg * 8 + i;
            const float4 p = p1s[R0 + nl];
            const float gv = g1s[R0 + nl];
            float aw[4];
#pragma unroll
            for (int m = 0; m < 4; m++) {
                float d = fmaf(qx[m], p.x, fmaf(qy[m], p.y, qz[m] * p.z));
                d = fminf(fmaxf(d, -1.f + 1e-6f), 1.f - 1e-6f);
                const float u = fabsf(d);
                float pl = fmaf(u, K3, K2); pl = fmaf(u, pl, K1); pl = fmaf(u, pl, K0);
                const float rt = __builtin_amdgcn_sqrtf(1.f - u) * pl;
                const float ach = (d >= 0.f) ? rt : (pi_ieh - rt);
                aw[m] = ach;
                v[m][i] = gv - ach;
            }
            *(float4*)&achT[nl][c0] = make_float4(aw[0], aw[1], aw[2], aw[3]);
        }
        if (!diag) {
#pragma unroll
            for (int m = 0; m < 4; m++) {
                float cm = v[m][0];
#pragma unroll
                for (int i = 1; i < 8; i++) cm = fmaxf(cm, v[m][i]);
                float s = 0.f;
#pragma unroll
                for (int i = 0; i < 8; i++) s += __builtin_amdgcn_exp2f(v[m][i] - cm);
                mredC[c0 + m][rg] = make_float2(cm, s);
            }
        }
        __syncthreads();   // achT + mredC ready

        if (!diag && t < TB) {   // merge 8 row-groups into colAcc[t]
            float M = -INFINITY, S = 0.f;
#pragma unroll
            for (int g = 0; g < 8; g++) {
                float2 pr = mredC[t][g];
                float nm = fmaxf(M, pr.x);
                S = S * __builtin_amdgcn_exp2f(M - nm) + pr.y * __builtin_amdgcn_exp2f(pr.x - nm);
                M = nm;
            }
            float2 ca = colAcc[t];
            float nm = fmaxf(ca.x, M);
            colAcc[t] = make_float2(nm, ca.y * __builtin_amdgcn_exp2f(ca.x - nm)
                                        + S * __builtin_amdgcn_exp2f(M - nm));
        }

        // ---- phase B: row-dir over achT ----
        {
            const int r = t >> 2, cq = t & 3;
            float M = -INFINITY, S = 0.f;
#pragma unroll
            for (int ch = 0; ch < 8; ch++) {
                const int cb = cq * 32 + ch * 4;
                const float4 av = *(const float4*)&achT[r][cb];
                const float4 gw = *(const float4*)&g2s[cb];
                const float w0 = gw.x - av.x, w1 = gw.y - av.y;
                const float w2 = gw.z - av.z, w3 = gw.w - av.w;
                const float cm = fmaxf(fmaxf(w0, w1), fmaxf(w2, w3));
                const float nm = fmaxf(M, cm);
                S = S * __builtin_amdgcn_exp2f(M - nm)
                  + __builtin_amdgcn_exp2f(w0 - nm) + __builtin_amdgcn_exp2f(w1 - nm)
                  + __builtin_amdgcn_exp2f(w2 - nm) + __builtin_amdgcn_exp2f(w3 - nm);
                M = nm;
            }
            mredR[r][cq] = make_float2(M, S);
        }
        __syncthreads();   // mredR ready; all achT/mredC reads done

        if (t < 64) {      // merge 4 col-quarters, write row partial
            float M = -INFINITY, S = 0.f;
#pragma unroll
            for (int w = 0; w < 4; w++) {
                float2 pr = mredR[t][w];
                float nm = fmaxf(M, pr.x);
                S = S * __builtin_amdgcn_exp2f(M - nm) + pr.y * __builtin_amdgcn_exp2f(pr.x - nm);
                M = nm;
            }
            size_t gr = (size_t)b * NN + (size_t)I * TB + R0 + t;
            rowArr[gr * SLOTS + J] = make_float2(M, S);
        }
    }

    if (!diag && t < TB) {
        size_t gc = (size_t)b * NN + (size_t)J * TB + t;
        colArr[gc * SLOTS + I] = colAcc[t];
    }
}

// ---------------------------------------------------------------------------
// combine: merge 16 partials per (output, b, n); apply -eps*ln2*(M+log2 S),
// optional 0.5-averaging; emit next-step g arrays (log2 domain).
// ---------------------------------------------------------------------------
__global__ __launch_bounds__(256)
void combine_kernel(const float2* __restrict__ pAX, const float2* __restrict__ pBY,
                    const float2* __restrict__ pAY, const float2* __restrict__ pBX,
                    float* a_x, float* b_y, float* a_y, float* b_x,
                    const float* __restrict__ gxw, const float* __restrict__ gyw,
                    float* gA, float* gB, float* gXs, float* gYs,
                    float eps_ln2, float nieL2E, int do_avg)
{
    int gid = blockIdx.x * 256 + threadIdx.x;     // 4*SARR threads
    int o = gid >> 14, i = gid & (SARR - 1);
    const float2* P = (o == 0) ? pAX : (o == 1) ? pBY : (o == 2) ? pAY : pBX;
    float* pot = (o == 0) ? a_x : (o == 1) ? b_y : (o == 2) ? a_y : b_x;
    const float2* row = P + (size_t)i * SLOTS;
    float M = -INFINITY, S = 0.f;
#pragma unroll
    for (int s = 0; s < SLOTS; s++) {
        float2 pr = row[s];
        float nm = fmaxf(M, pr.x);
        S = S * __builtin_amdgcn_exp2f(M - nm) + pr.y * __builtin_amdgcn_exp2f(pr.x - nm);
        M = nm;
    }
    float r = -eps_ln2 * (M + __builtin_amdgcn_logf(S));
    if (do_avg) r = 0.5f * (r + pot[i]);
    pot[i] = r;
    float gr = r * nieL2E;
    if (o == 0)      gA[i]  = gxw[i] + gr;
    else if (o == 1) gB[i]  = gyw[i] + gr;
    else if (o == 2) gYs[i] = gyw[i] + gr;
    else             gXs[i] = gxw[i] + gr;
}

// ---------------------------------------------------------------------------
__global__ __launch_bounds__(256)
void reduce_kernel(const float* __restrict__ alpha, const float* __restrict__ beta,
                   const float* __restrict__ a_x, const float* __restrict__ b_x,
                   const float* __restrict__ a_y, const float* __restrict__ b_y,
                   float* __restrict__ out)
{
    const int b = blockIdx.x, tid = threadIdx.x;
    float acc = 0.f;
    for (int n = tid; n < NN; n += 256) {
        const size_t i = (size_t)b * NN + n;
        acc += alpha[i] * (b_x[i] - a_x[i]);
        acc += beta[i] * (a_y[i] - b_y[i]);
    }
    __shared__ float red[256];
    red[tid] = acc;
    __syncthreads();
    for (int st = 128; st > 0; st >>= 1) {
        if (tid < st) red[tid] += red[tid + st];
        __syncthreads();
    }
    if (tid == 0) out[b] = red[0];
}

// ---------------------------------------------------------------------------
extern "C" void kernel_launch(void* const* d_in, const int* in_sizes, int n_in,
                              void* d_out, int out_size, void* d_ws, size_t ws_size,
                              hipStream_t stream)
{
    const float* alpha = (const float*)d_in[0];
    const float* x     = (const float*)d_in[1];
    const float* beta  = (const float*)d_in[2];
    const float* y     = (const float*)d_in[3];
    float* out = (float*)d_out;
    float* ws  = (float*)d_ws;

    const size_t S = SARR;
    float* gxw = ws;          float* gyw = ws + S;
    float* gA  = ws + 2 * S;  float* gB  = ws + 3 * S;
    float* gXs = ws + 4 * S;  float* gYs = ws + 5 * S;
    float* ax  = ws + 6 * S;  float* by  = ws + 7 * S;
    float* ay  = ws + 8 * S;  float* bx  = ws + 9 * S;
    const size_t PSZ = (size_t)SARR * SLOTS;      // float2 count per partial array
    float2* pAX = (float2*)(ws + 10 * S);
    float2* pBY = pAX + PSZ;
    float2* pAY = pBY + PSZ;
    float2* pBX = pAY + PSZ;

    const float EPS[8] = {4.0f, 4.0f, 1.0f, 0.25f, 0.0625f, 0.015625f, 0.00390625f, 0.0025f};

    pack_kernel<<<SARR / 256, 256, 0, stream>>>(alpha, beta, gxw, gyw, gA, gB, gXs, gYs, SARR);

    TileArgs TA;
    TA.x = x; TA.y = y;
    TA.gA = gA; TA.gB = gB; TA.gXs = gXs; TA.gYs = gYs;
    TA.pAX = pAX; TA.pBY = pBY; TA.pAY = pAY; TA.pBX = pBX;

    const dim3 tg(NT, BB);
    auto step = [&](float e, float next_e, int avg) {
        const float ieh = 0.5f * (1.f / e) * L2E;
        tile_kernel<<<tg, 256, 0, stream>>>(TA, ieh, PI_F * ieh);
        combine_kernel<<<(4 * SARR) / 256, 256, 0, stream>>>(
            pAX, pBY, pAY, pBX, ax, by, ay, bx, gxw, gyw, gA, gB, gXs, gYs,
            e * LN2, (1.f / next_e) * L2E, avg);
    };

    step(EPS[0], EPS[0], 0);                                   // init
    for (int k = 0; k < 8; k++) step(EPS[k], (k < 7) ? EPS[k + 1] : EPS[7], 1);
    step(EPS[7], EPS[7], 0);                                   // final extrapolation

    reduce_kernel<<<BB, 256, 0, stream>>>(alpha, beta, ax, bx, ay, by, out);
}

// Round 6
// 651.928 us; speedup vs baseline: 3.5290x; 1.0865x over previous
//
#include <hip/hip_runtime.h>
#include <math.h>

// Problem constants: B=8, N=M=2048, D=3.
#define BB 8
#define NN 2048
#define L2E 1.4426950408889634f
#define LN2 0.6931471805599453f
#define PI_F 3.14159265358979f
#define CLIP 0.999999f

constexpr int TB   = 128;
constexpr int T16  = NN / TB;              // 16
constexpr int NXX  = T16 * (T16 + 1) / 2;  // 136
constexpr int NT   = 2 * NXX + T16 * T16;  // 528 tiles per batch
constexpr int SARR = BB * NN;              // 16384

// tile index -> (kind, I, J). kind 0: xx (I<=J), 1: yy (I<=J), 2: xy (all)
__device__ __forceinline__ void decode_tile(int bx, int& kind, int& I, int& J) {
    if (bx < NXX) kind = 0;
    else if (bx < 2 * NXX) { kind = 1; bx -= NXX; }
    else { kind = 2; bx -= 2 * NXX; }
    if (kind < 2) {
        int idx = bx; I = 0;
        for (;;) { int len = T16 - I; if (idx < len) { J = I + idx; break; } idx -= len; I++; }
    } else { I = bx >> 4; J = bx & 15; }
}

// scaled acos: acos(d) * ieh via A&S 4.4.45 (coeffs pre-scaled into K0..K3)
__device__ __forceinline__ float sacos(float d, float K0, float K1, float K2,
                                       float K3, float pi_ieh) {
    const float u = fabsf(d);
    float pl = fmaf(u, K3, K2); pl = fmaf(u, pl, K1); pl = fmaf(u, pl, K0);
    const float rt = __builtin_amdgcn_sqrtf(1.f - u) * pl;
    return (d >= 0.f) ? rt : (pi_ieh - rt);
}

// ---------------------------------------------------------------------------
// pack: initial g = log_weights * log2(e); emit W = 2^{g-G}, per-128-block G.
// o in {0:a_x(x),1:b_y(y),2:a_y-side(y),3:b_x-side(x)}
// ---------------------------------------------------------------------------
__global__ __launch_bounds__(256)
void pack_kernel(const float* __restrict__ alpha, const float* __restrict__ beta,
                 float* __restrict__ gxw, float* __restrict__ gyw,
                 float* __restrict__ Wall, float* __restrict__ Gall)
{
    const int tid = threadIdx.x;
    const int gid = blockIdx.x * 256 + tid;
    const int o = gid >> 14, i = gid & (SARR - 1);
    const float* w = (o == 0 || o == 3) ? alpha : beta;
    const float v = w[i];
    const float g = ((v > 0.f) ? logf(fmaxf(v, 1e-30f)) : -1e5f) * L2E;
    if (o == 0) gxw[i] = g;
    if (o == 1) gyw[i] = g;
    __shared__ float red[256];
    red[tid] = g;
    __syncthreads();
    const int base = tid & 128, loc = tid & 127;
    for (int st = 64; st; st >>= 1) {
        if (loc < st) red[base + loc] = fmaxf(red[base + loc], red[base + loc + st]);
        __syncthreads();
    }
    const float G = red[base];
    Wall[gid] = __builtin_amdgcn_exp2f(g - G);
    if (loc == 0) Gall[gid >> 7] = G;
}

// ---------------------------------------------------------------------------
// One-time geometry pass over FULL tile grids (kind = blockIdx.z):
//   rowmax R*[b][J][n] = max_{m in tile J} dot(p1_n, p2_m)  (n global row)
//   kind 2 additionally colmax Cxy[b][I][m] = max_{n in tile I} dot(x_n, y_m)
// xx/yy col shifts come from R by symmetry.
// ---------------------------------------------------------------------------
__global__ __launch_bounds__(256)
void maxes_kernel(const float* __restrict__ x, const float* __restrict__ y,
                  float* __restrict__ Rxx, float* __restrict__ Ryy,
                  float* __restrict__ Rxy, float* __restrict__ Cxy)
{
    __shared__ float4 p1s[TB], p2s[TB];
    __shared__ float colred[4][TB];
    const int I = blockIdx.x >> 4, J = blockIdx.x & 15;
    const int b = blockIdx.y, kind = blockIdx.z, t = threadIdx.x;
    const float* P1 = (kind == 1) ? y : x;
    const float* P2 = (kind == 0) ? x : y;
    if (t < TB) {
        size_t gi = (size_t)b * NN + (size_t)I * TB + t;
        p1s[t] = make_float4(P1[gi * 3], P1[gi * 3 + 1], P1[gi * 3 + 2], 0.f);
    } else {
        int u = t - TB; size_t gi = (size_t)b * NN + (size_t)J * TB + u;
        p2s[u] = make_float4(P2[gi * 3], P2[gi * 3 + 1], P2[gi * 3 + 2], 0.f);
    }
    __syncthreads();
    const int lane = t & 63, wv = t >> 6, colg = lane & 7, rowg = lane >> 3;
    const int r0 = wv * 32 + rowg * 4;
    float4 pr[4];
#pragma unroll
    for (int rr = 0; rr < 4; rr++) pr[rr] = p1s[r0 + rr];
    float rmx[4] = {-2.f, -2.f, -2.f, -2.f};
    float cmx[16];
#pragma unroll
    for (int j = 0; j < 16; j++) cmx[j] = -2.f;
#pragma unroll
    for (int j = 0; j < 16; j++) {
        const float4 q = p2s[colg + 8 * j];
#pragma unroll
        for (int rr = 0; rr < 4; rr++) {
            float d = fmaf(pr[rr].x, q.x, fmaf(pr[rr].y, q.y, pr[rr].z * q.z));
            rmx[rr] = fmaxf(rmx[rr], d);
            cmx[j] = fmaxf(cmx[j], d);
        }
    }
#pragma unroll
    for (int rr = 0; rr < 4; rr++) {
        float v = rmx[rr];
        v = fmaxf(v, __shfl_xor(v, 1)); v = fmaxf(v, __shfl_xor(v, 2));
        v = fmaxf(v, __shfl_xor(v, 4));
        rmx[rr] = v;
    }
    if (colg == 0) {
        float* R = (kind == 0) ? Rxx : (kind == 1) ? Ryy : Rxy;
        const size_t base = ((size_t)b * T16 + J) * NN + (size_t)I * TB + r0;
#pragma unroll
        for (int rr = 0; rr < 4; rr++) R[base + rr] = rmx[rr];
    }
    if (kind == 2) {
#pragma unroll
        for (int j = 0; j < 16; j++) {
            float v = cmx[j];
            v = fmaxf(v, __shfl_xor(v, 8)); v = fmaxf(v, __shfl_xor(v, 16));
            v = fmaxf(v, __shfl_xor(v, 32));
            cmx[j] = v;
        }
        if (rowg == 0) {
#pragma unroll
            for (int j = 0; j < 16; j++) colred[wv][colg + 8 * j] = cmx[j];
        }
        __syncthreads();
        if (t < TB) {
            const float v = fmaxf(fmaxf(colred[0][t], colred[1][t]),
                                  fmaxf(colred[2][t], colred[3][t]));
            Cxy[((size_t)b * T16 + I) * NN + (size_t)J * TB + t] = v;
        }
    }
}

// ---------------------------------------------------------------------------
// Tile kernel: ach computed once per pair; row acc += W2[m]*2^{s_r-ach},
// col acc += W1[n]*2^{s_c-ach} with per-row / per-col shifts (no underflow of
// dominant terms). Partials: row (G2 - s_r, rowsum); col (G1 - s_c, colsum).
// ---------------------------------------------------------------------------
struct TileArgs {
    const float* x; const float* y;
    const float* Wall; const float* Gall;
    const float* Rxx; const float* Ryy; const float* Rxy; const float* Cxy;
    float2* pAX; float2* pBY; float2* pAY; float2* pBX;
};

__global__ __launch_bounds__(256)
void tile_kernel(TileArgs A, float ieh, float pi_ieh)
{
    __shared__ float4 p1s[TB], p2s[TB];   // {px,py,pz,W}
    __shared__ float srs[TB], scs[TB];    // per-row / per-col shifts
    __shared__ float colpart[4][TB];
    int kind, I, J; decode_tile(blockIdx.x, kind, I, J);
    const int b = blockIdx.y, t = threadIdx.x;
    const float* P1 = (kind == 1) ? A.y : A.x;
    const float* P2 = (kind == 0) ? A.x : A.y;
    const int o1 = (kind == 0) ? 0 : (kind == 1) ? 1 : 3;   // row-side weights
    const int o2 = (kind == 0) ? 0 : (kind == 1) ? 1 : 2;   // col-side weights
    float2* rowOut = (kind == 0) ? A.pAX : (kind == 1) ? A.pBY : A.pBX;
    float2* colOut = (kind == 0) ? A.pAX : (kind == 1) ? A.pBY : A.pAY;
    const bool diag = (kind < 2) && (I == J);
    const float* W1 = A.Wall + (size_t)o1 * SARR;
    const float* W2 = A.Wall + (size_t)o2 * SARR;
    const float* Rrow = (kind == 0) ? A.Rxx : (kind == 1) ? A.Ryy : A.Rxy;
    const float* Csrc = (kind == 0) ? A.Rxx : (kind == 1) ? A.Ryy : A.Cxy;

    // acos poly (A&S 4.4.45), coefficients pre-scaled by ieh (log2 domain)
    const float K0 = 1.5707288f * ieh, K1 = -0.2121144f * ieh;
    const float K2 = 0.0742610f * ieh, K3 = -0.0187293f * ieh;

    if (t < TB) {
        size_t gi = (size_t)b * NN + (size_t)I * TB + t;
        p1s[t] = make_float4(P1[gi * 3], P1[gi * 3 + 1], P1[gi * 3 + 2], W1[gi]);
        float mdv = Rrow[((size_t)b * T16 + J) * NN + (size_t)I * TB + t];
        mdv = fminf(fmaxf(mdv, -CLIP), CLIP);
        srs[t] = sacos(mdv, K0, K1, K2, K3, pi_ieh);
    } else {
        int u = t - TB; size_t gi = (size_t)b * NN + (size_t)J * TB + u;
        p2s[u] = make_float4(P2[gi * 3], P2[gi * 3 + 1], P2[gi * 3 + 2], W2[gi]);
        float mdv = Csrc[((size_t)b * T16 + I) * NN + (size_t)J * TB + u];
        mdv = fminf(fmaxf(mdv, -CLIP), CLIP);
        scs[u] = sacos(mdv, K0, K1, K2, K3, pi_ieh);
    }

    const float G1 = A.Gall[o1 * 128 + b * T16 + I];
    const float G2 = A.Gall[o2 * 128 + b * T16 + J];

    __syncthreads();

    const int lane = t & 63, wv = t >> 6, colg = lane & 7, rowg = lane >> 3;
    const int r0 = wv * 32 + rowg * 4;
    float4 pr[4]; float srr[4];
#pragma unroll
    for (int rr = 0; rr < 4; rr++) { pr[rr] = p1s[r0 + rr]; srr[rr] = srs[r0 + rr]; }
    float racc[4] = {0.f, 0.f, 0.f, 0.f};
    float cacc[16];
#pragma unroll
    for (int j = 0; j < 16; j++) cacc[j] = 0.f;

#pragma unroll
    for (int j = 0; j < 16; j++) {
        const float4 q = p2s[colg + 8 * j];
        const float sc = scs[colg + 8 * j];
#pragma unroll
        for (int rr = 0; rr < 4; rr++) {
            const float4 p = pr[rr];
            float d = fmaf(p.x, q.x, fmaf(p.y, q.y, p.z * q.z));
            d = fminf(fmaxf(d, -CLIP), CLIP);
            const float ach = sacos(d, K0, K1, K2, K3, pi_ieh);
            const float er = __builtin_amdgcn_exp2f(srr[rr] - ach);
            const float ec = __builtin_amdgcn_exp2f(sc - ach);
            racc[rr] = fmaf(q.w, er, racc[rr]);
            cacc[j]  = fmaf(p.w, ec, cacc[j]);
        }
    }

    // col sums: reduce across rowg (lane bits 3..5)
#pragma unroll
    for (int j = 0; j < 16; j++) {
        float v = cacc[j];
        v += __shfl_xor(v, 8); v += __shfl_xor(v, 16); v += __shfl_xor(v, 32);
        cacc[j] = v;
    }
    if (rowg == 0) {
#pragma unroll
        for (int j = 0; j < 16; j++) colpart[wv][colg + 8 * j] = cacc[j];
    }
    // row sums: reduce across colg (lane bits 0..2)
#pragma unroll
    for (int rr = 0; rr < 4; rr++) {
        float v = racc[rr];
        v += __shfl_xor(v, 1); v += __shfl_xor(v, 2); v += __shfl_xor(v, 4);
        racc[rr] = v;
    }
    if (colg == 0) {
        const size_t gr = (size_t)b * NN + (size_t)I * TB + r0;
#pragma unroll
        for (int rr = 0; rr < 4; rr++)
            rowOut[(gr + rr) * T16 + J] = make_float2(G2 - srr[rr], racc[rr]);
    }
    __syncthreads();
    if (!diag && t < TB) {
        const float v = colpart[0][t] + colpart[1][t] + colpart[2][t] + colpart[3][t];
        const size_t gc = (size_t)b * NN + (size_t)J * TB + t;
        colOut[gc * T16 + I] = make_float2(G1 - scs[t], v);
    }
}

// ---------------------------------------------------------------------------
// combine: merge 16 (M,S) partials per row; r = -eps*ln2*(M+log2 S); optional
// 0.5-averaging; emit next-step W = 2^{g-G} and per-block G.
// ---------------------------------------------------------------------------
__global__ __launch_bounds__(256)
void combine_kernel(const float2* __restrict__ pAX, const float2* __restrict__ pBY,
                    const float2* __restrict__ pAY, const float2* __restrict__ pBX,
                    float* __restrict__ ax, float* __restrict__ by,
                    float* __restrict__ ay, float* __restrict__ bx,
                    const float* __restrict__ gxw, const float* __restrict__ gyw,
                    float* __restrict__ Wall, float* __restrict__ Gall,
                    float eps_ln2, float nieL2E, int do_avg)
{
    const int tid = threadIdx.x;
    const int gid = blockIdx.x * 256 + tid;
    const int o = gid >> 14, i = gid & (SARR - 1);
    const float2* P = (o == 0) ? pAX : (o == 1) ? pBY : (o == 2) ? pAY : pBX;
    float* pot = (o == 0) ? ax : (o == 1) ? by : (o == 2) ? ay : bx;
    const float2* row = P + (size_t)i * T16;
    float M = -INFINITY, S = 0.f;
#pragma unroll
    for (int u = 0; u < T16; u++) {
        const float2 pr = row[u];
        if (pr.y > 0.f) {
            const float nm = fmaxf(M, pr.x);
            S = S * __builtin_amdgcn_exp2f(M - nm) + pr.y * __builtin_amdgcn_exp2f(pr.x - nm);
            M = nm;
        }
    }
    S = fmaxf(S, 1e-38f);
    float r = -eps_ln2 * (M + __builtin_amdgcn_logf(S));
    if (do_avg) r = 0.5f * (r + pot[i]);
    pot[i] = r;
    const float g = ((o == 0 || o == 3) ? gxw[i] : gyw[i]) + r * nieL2E;
    __shared__ float red[256];
    red[tid] = g;
    __syncthreads();
    const int base = tid & 128, loc = tid & 127;
    for (int st = 64; st; st >>= 1) {
        if (loc < st) red[base + loc] = fmaxf(red[base + loc], red[base + loc + st]);
        __syncthreads();
    }
    const float G = red[base];
    Wall[gid] = __builtin_amdgcn_exp2f(g - G);
    if (loc == 0) Gall[gid >> 7] = G;
}

// ---------------------------------------------------------------------------
__global__ __launch_bounds__(256)
void reduce_kernel(const float* __restrict__ alpha, const float* __restrict__ beta,
                   const float* __restrict__ a_x, const float* __restrict__ b_x,
                   const float* __restrict__ a_y, const float* __restrict__ b_y,
                   float* __restrict__ out)
{
    const int b = blockIdx.x, tid = threadIdx.x;
    float acc = 0.f;
    for (int n = tid; n < NN; n += 256) {
        const size_t i = (size_t)b * NN + n;
        acc += alpha[i] * (b_x[i] - a_x[i]);
        acc += beta[i] * (a_y[i] - b_y[i]);
    }
    __shared__ float red[256];
    red[tid] = acc;
    __syncthreads();
    for (int st = 128; st > 0; st >>= 1) {
        if (tid < st) red[tid] += red[tid + st];
        __syncthreads();
    }
    if (tid == 0) out[b] = red[0];
}

// ---------------------------------------------------------------------------
extern "C" void kernel_launch(void* const* d_in, const int* in_sizes, int n_in,
                              void* d_out, int out_size, void* d_ws, size_t ws_size,
                              hipStream_t stream)
{
    const float* alpha = (const float*)d_in[0];
    const float* x     = (const float*)d_in[1];
    const float* beta  = (const float*)d_in[2];
    const float* y     = (const float*)d_in[3];
    float* out = (float*)d_out;
    float* ws  = (float*)d_ws;

    const size_t S = SARR;
    float* gxw  = ws;
    float* gyw  = ws + S;
    float* ax   = ws + 2 * S;
    float* by   = ws + 3 * S;
    float* ay   = ws + 4 * S;
    float* bx   = ws + 5 * S;
    float* Wall = ws + 6 * S;              // 4*S
    float* Gall = ws + 10 * S;             // 512
    float* Rxx  = ws + 10 * S + 512;       // 16*S each
    float* Ryy  = Rxx + 16 * S;
    float* Rxy  = Ryy + 16 * S;
    float* Cxy  = Rxy + 16 * S;
    float* pb   = Cxy + 16 * S;
    const size_t PSZ = (size_t)SARR * T16; // float2 count per partial array
    float2* pAX = (float2*)pb;
    float2* pBY = pAX + PSZ;
    float2* pAY = pBY + PSZ;
    float2* pBX = pAY + PSZ;

    const float EPS[8] = {4.0f, 4.0f, 1.0f, 0.25f, 0.0625f, 0.015625f, 0.00390625f, 0.0025f};

    pack_kernel<<<(4 * SARR) / 256, 256, 0, stream>>>(alpha, beta, gxw, gyw, Wall, Gall);
    maxes_kernel<<<dim3(256, BB, 3), 256, 0, stream>>>(x, y, Rxx, Ryy, Rxy, Cxy);

    TileArgs TA;
    TA.x = x; TA.y = y; TA.Wall = Wall; TA.Gall = Gall;
    TA.Rxx = Rxx; TA.Ryy = Ryy; TA.Rxy = Rxy; TA.Cxy = Cxy;
    TA.pAX = pAX; TA.pBY = pBY; TA.pAY = pAY; TA.pBX = pBX;

    auto step = [&](float e, float next_e, int avg) {
        const float ieh = 0.5f * (1.f / e) * L2E;
        tile_kernel<<<dim3(NT, BB), 256, 0, stream>>>(TA, ieh, PI_F * ieh);
        combine_kernel<<<(4 * SARR) / 256, 256, 0, stream>>>(
            pAX, pBY, pAY, pBX, ax, by, ay, bx, gxw, gyw, Wall, Gall,
            e * LN2, (1.f / next_e) * L2E, avg);
    };

    step(EPS[0], EPS[0], 0);                                   // init
    for (int k = 0; k < 8; k++) step(EPS[k], (k < 7) ? EPS[k + 1] : EPS[7], 1);
    step(EPS[7], EPS[7], 0);                                   // final extrapolation

    reduce_kernel<<<BB, 256, 0, stream>>>(alpha, beta, ax, bx, ay, by, out);
}